// Round 13
// baseline (47.051 us; speedup 1.0000x reference)
//
#include <hip/hip_runtime.h>
#include <hip/hip_bf16.h>
#include <math.h>

#define NROW 4096
#define DIM  512
#define M2   8192                     // 2N rows
#define SELF_EXP 7.3890560989306495f  // exp(1/T) = exp(2)
#define NBLK  1056                    // sum_{n=0..63} (n/2+1), 8*132
#define BK    64                      // K-step (int8 elements) -> 64 B rows
#define NKS   (DIM / BK)              // 8 K-steps
#define STEPB 24576                   // per-step LDS: A 16K + B 8K
#define LDS_TOTAL (3 * STEPB)         // 72 KiB ring-3 -> 2 blk/CU
#define INV127SQ (1.0f / 16129.0f)    // 1/127^2 dequant scale

typedef __attribute__((ext_vector_type(4))) int   i32x4;    // 16 int8 / i32 C
typedef __attribute__((ext_vector_type(4))) float f32x4;

// ---------------------------------------------------------------------------
// Kernel 1: fused row-normalize (x,y -> int8 q = round(127*v_hat)) + positive-
// pair cosine partial (EXACT fp32 path) + rowsum zeroing + out zeroing.
// float4 loads, 2 rows per 256-thr block (R8-verified, ~75% of HBM ceiling).
// ---------------------------------------------------------------------------
__global__ __launch_bounds__(256) void norm_pos_kernel(
    const float* __restrict__ x, const float* __restrict__ y,
    unsigned char* __restrict__ ns, float* __restrict__ pospart,
    float* __restrict__ rowsum, float* __restrict__ out)
{
    const int b = blockIdx.x;            // 0..2047
    const int t = threadIdx.x;           // 0..255
    const int h = t >> 7;                // row half within block
    const int u = t & 127;               // lane within row
    const int r = b * 2 + h;             // global row 0..4095

    const float4 a = ((const float4*)(x + (size_t)r * DIM))[u];
    const float4 c = ((const float4*)(y + (size_t)r * DIM))[u];
    float sx = a.x * a.x + a.y * a.y + a.z * a.z + a.w * a.w;
    float sy = c.x * c.x + c.y * c.y + c.z * c.z + c.w * c.w;
    float dt = a.x * c.x + a.y * c.y + a.z * c.z + a.w * c.w;
    #pragma unroll
    for (int o = 1; o < 64; o <<= 1) {
        sx += __shfl_xor(sx, o);
        sy += __shfl_xor(sy, o);
        dt += __shfl_xor(dt, o);
    }
    __shared__ float rd[4][3];
    const int w = t >> 6;                // wave 0..3 (waves 2h,2h+1 = row h)
    if ((t & 63) == 0) { rd[w][0] = sx; rd[w][1] = sy; rd[w][2] = dt; }
    __syncthreads();
    const float SX = rd[2 * h][0] + rd[2 * h + 1][0];
    const float SY = rd[2 * h][1] + rd[2 * h + 1][1];
    const float D  = rd[2 * h][2] + rd[2 * h + 1][2];
    const float rnx = rsqrtf(SX), rny = rsqrtf(SY);

    // unit-vector components in [-1,1] -> q in [-127,127], no clamp needed
    uchar4 qa, qc;
    qa.x = (unsigned char)(__float2int_rn(a.x * rnx * 127.f) & 0xff);
    qa.y = (unsigned char)(__float2int_rn(a.y * rnx * 127.f) & 0xff);
    qa.z = (unsigned char)(__float2int_rn(a.z * rnx * 127.f) & 0xff);
    qa.w = (unsigned char)(__float2int_rn(a.w * rnx * 127.f) & 0xff);
    qc.x = (unsigned char)(__float2int_rn(c.x * rny * 127.f) & 0xff);
    qc.y = (unsigned char)(__float2int_rn(c.y * rny * 127.f) & 0xff);
    qc.z = (unsigned char)(__float2int_rn(c.z * rny * 127.f) & 0xff);
    qc.w = (unsigned char)(__float2int_rn(c.w * rny * 127.f) & 0xff);
    ((uchar4*)(void*)(ns + (size_t)r * DIM))[u] = qa;
    ((uchar4*)(void*)(ns + (size_t)(r + NROW) * DIM))[u] = qc;

    if (u == 0) pospart[r] = D * rnx * rny;
    if (t < 4)  rowsum[4 * b + t] = 0.f;
    if (b == 0 && t == 0) out[0] = 0.f;
}

// ---------------------------------------------------------------------------
// Kernel 2: symmetric Gram (int8, mfma_i32_16x16x64_i8, exact int32 accum).
// R13: 256x128 tile, 512 thr (8 waves), ring-3 x 24 KiB (72 KiB dyn LDS) ->
// 2 blk/CU x 8 waves = 16 waves/CU (UP from 12) while tile count drops
// 2080 -> 1056: barrier rounds per CU halve (R9 mechanism) WITHOUT the
// occupancy loss that killed R11. Inner loop per wave byte-identical to the
// verified kernel (4 av + 4 bv ds_reads, 16 MFMA, 64-reg acc, same swizzle).
// Tiling: column-block n (128 cols) x row-pair p (256 rows = 128-blocks
// 2p,2p+1); c(n)=n/2+1 tiles/col; S(2t)=t^2+t, S(2t+1)=(t+1)^2. Per-wave:
// blk=2p+(wr>>1); blk>n idle (1.5% waste), blk==n diag (rowsum only),
// blk<n full (row+col) - old diag logic made per-wave.
// CONSTRAINT MAP: (512,4) -> 128-reg cap (R3/R6 spill line respected);
// operands stream through LDS only (R10); counted vmcnt(3) until tail
// (R7/R9); >=12 waves/CU (R11).
// ---------------------------------------------------------------------------
__device__ __forceinline__ void stage_tiles(
    const char* nsb, char* buf, int p, int n, int koff, int t)
{
    #pragma unroll
    for (int l = 0; l < 3; ++l) {                 // exactly 3 loads/thread
        const int chunk = l * 512 + t;            // 0..1535 16B chunks
        const int isB   = chunk >> 10;            // l=0,1: A  l=2: B (uniform)
        const int o     = (chunk & (isB ? 511 : 1023)) * 16;
        const int row   = o >> 6;                 // A:0..255  B:0..127
        const int slot  = (o >> 4) & 3;
        const int src   = (slot ^ ((row >> 1) & 3)) << 4;  // inverse swizzle
        const int grow  = isB ? (n * 128 + row) : (p * 256 + row);
        const char* gsrc = nsb + (size_t)grow * DIM + koff + src;  // 512 B rows
        char* ldst = buf + (isB << 14) + o;       // linear LDS dest
        __builtin_amdgcn_global_load_lds(
            (const __attribute__((address_space(1))) void*)gsrc,
            (__attribute__((address_space(3))) void*)ldst, 16, 0, 0);
    }
}

#define BARRIER() do { asm volatile("" ::: "memory");                          \
    __builtin_amdgcn_s_barrier(); asm volatile("" ::: "memory"); } while (0)
#define VMCNT(n) asm volatile("s_waitcnt vmcnt(" #n ")" ::: "memory")

__device__ __forceinline__ int Sfun(int nn)
{   // tiles before column nn
    const int tt = nn >> 1;
    return (nn & 1) ? (tt + 1) * (tt + 1) : tt * tt + tt;
}

__global__ __launch_bounds__(512, 4) void gram_rowsum_kernel(
    const unsigned char* __restrict__ ns, float* __restrict__ rowsum)
{
    extern __shared__ char ring[];     // 3 x 24576

    // XCD-chunked swizzle: 1056 % 8 == 0, each XCD gets 132 consecutive idx
    const int raw = blockIdx.x;
    const int idx = (raw & 7) * (NBLK / 8) + (raw >> 3);

    // decode: column-block n, row-pair p
    int n = (int)(2.0f * sqrtf((float)idx + 1.0f));
    if (n > 63) n = 63;
    while (n < 63 && Sfun(n + 1) <= idx) ++n;
    while (Sfun(n) > idx) --n;
    const int p = idx - Sfun(n);

    const int t = threadIdx.x;
    const int lane = t & 63;
    const int l15  = lane & 15;
    const int wid  = t >> 6;           // 0..7
    const int wr = wid >> 1;           // 0..3 (64-row band of 256)
    const int wc = wid & 1;            // 0..1 (64-col band of 128)
    const int blk  = 2 * p + (wr >> 1);  // this wave's 128-row block
    const bool act  = (blk <= n);
    const bool diag = (blk == n);

    i32x4 acc[4][4];
    #pragma unroll
    for (int m = 0; m < 4; ++m)
        #pragma unroll
        for (int nn = 0; nn < 4; ++nn)
            acc[m][nn] = (i32x4)0;

    const char* nsb = (const char*)ns;
    const int kb2 = (lane >> 4) * 16;        // byte offset of 16B k-slot

    // prologue: stage K-steps 0 and 1
    stage_tiles(nsb, ring + 0 * STEPB, p, n, 0, t);
    stage_tiles(nsb, ring + 1 * STEPB, p, n, BK, t);

    #pragma unroll
    for (int ks = 0; ks < NKS; ++ks) {       // fully unrolled: ks%3 is const
        // own stage(ks) complete (stage(ks+1) may stay in flight)
        if (ks < NKS - 1) VMCNT(3); else VMCNT(0);
        BARRIER();   // all waves: stage(ks) done AND buf[(ks-1)%3] reads done

        if (ks + 2 < NKS)
            stage_tiles(nsb, ring + ((ks + 2) % 3) * STEPB, p, n,
                        (ks + 2) * BK, t);
        __builtin_amdgcn_sched_barrier(0);   // keep stage issue above reads

        const char* A = ring + (ks % 3) * STEPB;
        const char* B = A + 16384;
        i32x4 av[4], bv[4];
        #pragma unroll
        for (int m = 0; m < 4; ++m) {
            const int row = wr * 64 + m * 16 + l15;      // 0..255
            const int sw  = ((row >> 1) & 3) << 4;
            av[m] = *(const i32x4*)(A + row * 64 + (kb2 ^ sw));
        }
        #pragma unroll
        for (int nn = 0; nn < 4; ++nn) {
            const int row = wc * 64 + nn * 16 + l15;     // 0..127
            const int sw  = ((row >> 1) & 3) << 4;
            bv[nn] = *(const i32x4*)(B + row * 64 + (kb2 ^ sw));
        }
        __builtin_amdgcn_s_setprio(1);
        if (act) {
            #pragma unroll
            for (int m = 0; m < 4; ++m)
                #pragma unroll
                for (int nn = 0; nn < 4; ++nn)
                    acc[m][nn] = __builtin_amdgcn_mfma_i32_16x16x64_i8(
                        av[m], bv[nn], acc[m][nn], 0, 0, 0);
        }
        __builtin_amdgcn_s_setprio(0);
    }

    // ---- epilogue: E = exp(2*acc/127^2); row sums; col sums if off-diag ---
    if (act) {
        f32x4 e[4][4];
        #pragma unroll
        for (int m = 0; m < 4; ++m)
            #pragma unroll
            for (int nn = 0; nn < 4; ++nn)
                #pragma unroll
                for (int r = 0; r < 4; ++r)
                    e[m][nn][r] = __expf((float)acc[m][nn][r] * (2.0f * INV127SQ));

        // C/D layout: row = m*16+(lane>>4)*4+reg ; col = nn*16+(lane&15)
        #pragma unroll
        for (int m = 0; m < 4; ++m) {
            #pragma unroll
            for (int reg = 0; reg < 4; ++reg) {
                float q = e[m][0][reg] + e[m][1][reg] + e[m][2][reg] + e[m][3][reg];
                q += __shfl_xor(q, 1);
                q += __shfl_xor(q, 2);
                q += __shfl_xor(q, 4);
                q += __shfl_xor(q, 8);
                if (l15 == 0) {
                    const int row = p * 256 + wr * 64 + m * 16 + (lane >> 4) * 4 + reg;
                    atomicAdd(&rowsum[row], q);
                }
            }
        }
        if (!diag) {
            #pragma unroll
            for (int nn = 0; nn < 4; ++nn) {
                float q = 0.f;
                #pragma unroll
                for (int m = 0; m < 4; ++m)
                    #pragma unroll
                    for (int reg = 0; reg < 4; ++reg)
                        q += e[m][nn][reg];
                q += __shfl_xor(q, 16);
                q += __shfl_xor(q, 32);
                if (lane < 16) {
                    const int col = n * 128 + wc * 64 + nn * 16 + lane;
                    atomicAdd(&rowsum[col], q);
                }
            }
        }
    }
}

// ---------------------------------------------------------------------------
// Kernel 3: finalize -> loss, parallel (32 blocks, atomicAdd into out)
// ---------------------------------------------------------------------------
__global__ __launch_bounds__(256) void finalize_kernel(
    const float* __restrict__ rowsum, const float* __restrict__ pospart,
    float* __restrict__ out)
{
    const int b = blockIdx.x, t = threadIdx.x;
    float s  = logf(rowsum[b * 256 + t] - SELF_EXP);
    float pp = (t < 128) ? pospart[b * 128 + t] : 0.f;
    #pragma unroll
    for (int o = 1; o < 64; o <<= 1) {
        s  += __shfl_xor(s, o);
        pp += __shfl_xor(pp, o);
    }
    __shared__ float rd[8];
    if ((t & 63) == 0) { rd[t >> 6] = s; rd[4 + (t >> 6)] = pp; }
    __syncthreads();
    if (t == 0) {
        const float ts = rd[0] + rd[1] + rd[2] + rd[3];
        const float tp = rd[4] + rd[5] + rd[6] + rd[7];
        atomicAdd(out, (ts - 4.0f * tp) / (float)M2);
    }
}

// ---------------------------------------------------------------------------
extern "C" void kernel_launch(void* const* d_in, const int* in_sizes, int n_in,
                              void* d_out, int out_size, void* d_ws, size_t ws_size,
                              hipStream_t stream)
{
    const float* x = (const float*)d_in[0];
    const float* y = (const float*)d_in[1];
    float* out = (float*)d_out;

    char* ws = (char*)d_ws;
    unsigned char* ns = (unsigned char*)ws;                   // 4 MiB (int8)
    float* rowsum  = (float*)(ws + (size_t)4 * 1024 * 1024);  // 32 KiB
    float* pospart = rowsum + M2;                             // 16 KiB

    static bool attr_set = false;
    if (!attr_set) {
        (void)hipFuncSetAttribute((const void*)gram_rowsum_kernel,
                                  hipFuncAttributeMaxDynamicSharedMemorySize,
                                  LDS_TOTAL);
        attr_set = true;
    }

    norm_pos_kernel<<<NROW / 2, 256, 0, stream>>>(x, y, ns, pospart, rowsum, out);

    gram_rowsum_kernel<<<NBLK, 512, LDS_TOTAL, stream>>>(ns, rowsum);

    finalize_kernel<<<32, 256, 0, stream>>>(rowsum, pospart, out);
}

// Round 14
// 45.604 us; speedup vs baseline: 1.0317x; 1.0317x over previous
//
#include <hip/hip_runtime.h>
#include <hip/hip_bf16.h>
#include <math.h>

#define NROW 4096
#define DIM  512
#define M2   8192                     // 2N rows
#define SELF_EXP 7.3890560989306495f  // exp(1/T) = exp(2)
#define NTILE 64                      // M2 / 128
#define NBLK  (NTILE * (NTILE + 1) / 2)   // 2080 upper-triangle tiles (8*260)
#define BK    64                      // K-step (int8 elements) -> 64 B rows
#define NKS   (DIM / BK)              // 8 K-steps
#define INV127SQ (1.0f / 16129.0f)    // 1/127^2 dequant scale

typedef __attribute__((ext_vector_type(4))) int   i32x4;    // 16 int8 / i32 C
typedef __attribute__((ext_vector_type(4))) float f32x4;

// ---------------------------------------------------------------------------
// Kernel 1: fused row-normalize (x,y -> int8 q = round(127*v_hat)) + positive-
// pair cosine partial (EXACT fp32 path) + rowsum zeroing + out zeroing.
// float4 loads, 2 rows per 256-thr block (R8-verified, ~75% of HBM ceiling).
// ---------------------------------------------------------------------------
__global__ __launch_bounds__(256) void norm_pos_kernel(
    const float* __restrict__ x, const float* __restrict__ y,
    unsigned char* __restrict__ ns, float* __restrict__ pospart,
    float* __restrict__ rowsum, float* __restrict__ out)
{
    const int b = blockIdx.x;            // 0..2047
    const int t = threadIdx.x;           // 0..255
    const int h = t >> 7;                // row half within block
    const int u = t & 127;               // lane within row
    const int r = b * 2 + h;             // global row 0..4095

    const float4 a = ((const float4*)(x + (size_t)r * DIM))[u];
    const float4 c = ((const float4*)(y + (size_t)r * DIM))[u];
    float sx = a.x * a.x + a.y * a.y + a.z * a.z + a.w * a.w;
    float sy = c.x * c.x + c.y * c.y + c.z * c.z + c.w * c.w;
    float dt = a.x * c.x + a.y * c.y + a.z * c.z + a.w * c.w;
    #pragma unroll
    for (int o = 1; o < 64; o <<= 1) {
        sx += __shfl_xor(sx, o);
        sy += __shfl_xor(sy, o);
        dt += __shfl_xor(dt, o);
    }
    __shared__ float rd[4][3];
    const int w = t >> 6;                // wave 0..3 (waves 2h,2h+1 = row h)
    if ((t & 63) == 0) { rd[w][0] = sx; rd[w][1] = sy; rd[w][2] = dt; }
    __syncthreads();
    const float SX = rd[2 * h][0] + rd[2 * h + 1][0];
    const float SY = rd[2 * h][1] + rd[2 * h + 1][1];
    const float D  = rd[2 * h][2] + rd[2 * h + 1][2];
    const float rnx = rsqrtf(SX), rny = rsqrtf(SY);

    // unit-vector components in [-1,1] -> q in [-127,127], no clamp needed
    uchar4 qa, qc;
    qa.x = (unsigned char)(__float2int_rn(a.x * rnx * 127.f) & 0xff);
    qa.y = (unsigned char)(__float2int_rn(a.y * rnx * 127.f) & 0xff);
    qa.z = (unsigned char)(__float2int_rn(a.z * rnx * 127.f) & 0xff);
    qa.w = (unsigned char)(__float2int_rn(a.w * rnx * 127.f) & 0xff);
    qc.x = (unsigned char)(__float2int_rn(c.x * rny * 127.f) & 0xff);
    qc.y = (unsigned char)(__float2int_rn(c.y * rny * 127.f) & 0xff);
    qc.z = (unsigned char)(__float2int_rn(c.z * rny * 127.f) & 0xff);
    qc.w = (unsigned char)(__float2int_rn(c.w * rny * 127.f) & 0xff);
    ((uchar4*)(void*)(ns + (size_t)r * DIM))[u] = qa;
    ((uchar4*)(void*)(ns + (size_t)(r + NROW) * DIM))[u] = qc;

    if (u == 0) pospart[r] = D * rnx * rny;
    if (t < 4)  rowsum[4 * b + t] = 0.f;
    if (b == 0 && t == 0) out[0] = 0.f;
}

// ---------------------------------------------------------------------------
// Kernel 2: symmetric Gram (int8, mfma_i32_16x16x64_i8, exact int32 accum).
// R12-verified optimum (gram ~31 us): 128x128 tile, RING-3 LDS (3 x 16 KiB,
// 3 blk/CU = 12 waves), ONE merged barrier per K-step, counted vmcnt(4)
// until the tail, setprio(1) around MFMA (neutral but free), XCD-chunked
// blockIdx, both-sides slot swizzle (0 conflicts).
// COMPLETE STRUCTURE MAP (all hardware-measured, all alternatives regress):
//   tile: 64^2 / 128x256 / 256x128 (R13 +1.4us) / 256^2 (R1/R2) -> 128^2 best
//   ring: 2 (R7, 2-bar) / 4 / 5 (R11 +12us) -> ring-3 merged-bar best
//   occupancy: 2 blk/CU (R11) / cap 5 (R3 spills) -> 3 blk/CU best
//   dtype: bf16 / fp8 (R5) / MX-fp8 (R6 spills) / i8 (R7) -> i8 best
//   staging: global-direct A (R10, 2x slower) -> global_load_lds only
//   8-phase co-designed stack: failed twice (K=512 too shallow, 8 steps/tile)
// Residual ~2.3x over balanced-pipe floor = m97-class barrier-drain ceiling.
// ---------------------------------------------------------------------------
__device__ __forceinline__ void stage_tiles(
    const char* nsb, char* buf, int bi, int bj, int koff, int t)
{
    #pragma unroll
    for (int l = 0; l < 4; ++l) {                 // exactly 4 loads/thread
        const int chunk = l * 256 + t;            // 0..1023 16B chunks
        const int half  = chunk >> 9;             // 0:A 1:B (wave-uniform)
        const int o     = (chunk & 511) * 16;     // byte off within 8 KiB tile
        const int row   = o >> 6;                 // 64 B per LDS row
        const int slot  = (o >> 4) & 3;
        const int src   = (slot ^ ((row >> 1) & 3)) << 4;  // inverse swizzle
        const int grow  = (half ? bj : bi) * 128 + row;
        const char* gsrc = nsb + (size_t)grow * DIM + koff + src;  // 512 B rows
        char* ldst = buf + half * 8192 + o;       // linear LDS dest
        __builtin_amdgcn_global_load_lds(
            (const __attribute__((address_space(1))) void*)gsrc,
            (__attribute__((address_space(3))) void*)ldst, 16, 0, 0);
    }
}

#define BARRIER() do { asm volatile("" ::: "memory");                          \
    __builtin_amdgcn_s_barrier(); asm volatile("" ::: "memory"); } while (0)
#define VMCNT(n) asm volatile("s_waitcnt vmcnt(" #n ")" ::: "memory")

__global__ __launch_bounds__(256, 3) void gram_rowsum_kernel(
    const unsigned char* __restrict__ ns, float* __restrict__ rowsum)
{
    __shared__ char ring[3][16384];    // 3 x (A 8 KiB + B 8 KiB)

    // XCD-chunked swizzle: 2080 % 8 == 0, each XCD gets 260 consecutive idx
    const int raw = blockIdx.x;
    const int idx = (raw & 7) * (NBLK / 8) + (raw >> 3);

    // decode upper-triangle tile index: idx = bj*(bj+1)/2 + bi, bi <= bj
    int bj = (int)floorf((sqrtf(8.0f * (float)idx + 1.0f) - 1.0f) * 0.5f);
    while ((bj + 1) * (bj + 2) / 2 <= idx) ++bj;
    while (bj * (bj + 1) / 2 > idx) --bj;
    const int bi = idx - bj * (bj + 1) / 2;

    const int t = threadIdx.x;
    const int lane = t & 63;
    const int l15  = lane & 15;
    const int wid  = t >> 6;
    const int wr = wid >> 1, wc = wid & 1;   // wave quadrant (64x64)

    i32x4 acc[4][4];
    #pragma unroll
    for (int m = 0; m < 4; ++m)
        #pragma unroll
        for (int n = 0; n < 4; ++n)
            acc[m][n] = (i32x4)0;

    const char* nsb = (const char*)ns;
    const int kb2 = (lane >> 4) * 16;        // byte offset of 16B k-slot

    // prologue: stage K-steps 0 and 1
    stage_tiles(nsb, ring[0], bi, bj, 0, t);
    stage_tiles(nsb, ring[1], bi, bj, BK, t);

    #pragma unroll
    for (int ks = 0; ks < NKS; ++ks) {       // fully unrolled: ks%3 is const
        // own stage(ks) complete (stage(ks+1) may stay in flight)
        if (ks < NKS - 1) VMCNT(4); else VMCNT(0);
        BARRIER();   // all waves: stage(ks) done AND buf[(ks-1)%3] reads done

        if (ks + 2 < NKS)
            stage_tiles(nsb, ring[(ks + 2) % 3], bi, bj, (ks + 2) * BK, t);
        __builtin_amdgcn_sched_barrier(0);   // keep stage issue above reads

        const char* A = ring[ks % 3];
        const char* B = ring[ks % 3] + 8192;
        i32x4 av[4], bv[4];
        #pragma unroll
        for (int m = 0; m < 4; ++m) {
            const int row = wr * 64 + m * 16 + l15;
            const int sw  = ((row >> 1) & 3) << 4;
            av[m] = *(const i32x4*)(A + row * 64 + (kb2 ^ sw));
        }
        #pragma unroll
        for (int n = 0; n < 4; ++n) {
            const int row = wc * 64 + n * 16 + l15;
            const int sw  = ((row >> 1) & 3) << 4;
            bv[n] = *(const i32x4*)(B + row * 64 + (kb2 ^ sw));
        }
        // K=64 per step: ONE i8 MFMA per 16x16 subtile
        __builtin_amdgcn_s_setprio(1);
        #pragma unroll
        for (int m = 0; m < 4; ++m)
            #pragma unroll
            for (int n = 0; n < 4; ++n)
                acc[m][n] = __builtin_amdgcn_mfma_i32_16x16x64_i8(
                    av[m], bv[n], acc[m][n], 0, 0, 0);
        __builtin_amdgcn_s_setprio(0);
    }

    // ---- epilogue: E = exp(2*acc/127^2); row sums; col sums off-diagonal --
    f32x4 e[4][4];
    #pragma unroll
    for (int m = 0; m < 4; ++m)
        #pragma unroll
        for (int n = 0; n < 4; ++n)
            #pragma unroll
            for (int r = 0; r < 4; ++r)
                e[m][n][r] = __expf((float)acc[m][n][r] * (2.0f * INV127SQ));

    // C/D layout (dtype-independent): row = m*16+(lane>>4)*4+reg ; col = n*16+(lane&15)
    #pragma unroll
    for (int m = 0; m < 4; ++m) {
        #pragma unroll
        for (int reg = 0; reg < 4; ++reg) {
            float p = e[m][0][reg] + e[m][1][reg] + e[m][2][reg] + e[m][3][reg];
            p += __shfl_xor(p, 1);
            p += __shfl_xor(p, 2);
            p += __shfl_xor(p, 4);
            p += __shfl_xor(p, 8);
            if (l15 == 0) {
                const int row = bi * 128 + wr * 64 + m * 16 + (lane >> 4) * 4 + reg;
                atomicAdd(&rowsum[row], p);
            }
        }
    }
    if (bi != bj) {
        #pragma unroll
        for (int n = 0; n < 4; ++n) {
            float p = 0.f;
            #pragma unroll
            for (int m = 0; m < 4; ++m)
                #pragma unroll
                for (int reg = 0; reg < 4; ++reg)
                    p += e[m][n][reg];
            p += __shfl_xor(p, 16);
            p += __shfl_xor(p, 32);
            if (lane < 16) {
                const int col = bj * 128 + wc * 64 + n * 16 + lane;
                atomicAdd(&rowsum[col], p);
            }
        }
    }
}

// ---------------------------------------------------------------------------
// Kernel 3: finalize -> loss, parallel (32 blocks, atomicAdd into out)
// ---------------------------------------------------------------------------
__global__ __launch_bounds__(256) void finalize_kernel(
    const float* __restrict__ rowsum, const float* __restrict__ pospart,
    float* __restrict__ out)
{
    const int b = blockIdx.x, t = threadIdx.x;
    float s  = logf(rowsum[b * 256 + t] - SELF_EXP);
    float pp = (t < 128) ? pospart[b * 128 + t] : 0.f;
    #pragma unroll
    for (int o = 1; o < 64; o <<= 1) {
        s  += __shfl_xor(s, o);
        pp += __shfl_xor(pp, o);
    }
    __shared__ float rd[8];
    if ((t & 63) == 0) { rd[t >> 6] = s; rd[4 + (t >> 6)] = pp; }
    __syncthreads();
    if (t == 0) {
        const float ts = rd[0] + rd[1] + rd[2] + rd[3];
        const float tp = rd[4] + rd[5] + rd[6] + rd[7];
        atomicAdd(out, (ts - 4.0f * tp) / (float)M2);
    }
}

// ---------------------------------------------------------------------------
extern "C" void kernel_launch(void* const* d_in, const int* in_sizes, int n_in,
                              void* d_out, int out_size, void* d_ws, size_t ws_size,
                              hipStream_t stream)
{
    const float* x = (const float*)d_in[0];
    const float* y = (const float*)d_in[1];
    float* out = (float*)d_out;

    char* ws = (char*)d_ws;
    unsigned char* ns = (unsigned char*)ws;                   // 4 MiB (int8)
    float* rowsum  = (float*)(ws + (size_t)4 * 1024 * 1024);  // 32 KiB
    float* pospart = rowsum + M2;                             // 16 KiB

    norm_pos_kernel<<<NROW / 2, 256, 0, stream>>>(x, y, ns, pospart, rowsum, out);

    gram_rowsum_kernel<<<NBLK, 256, 0, stream>>>(ns, rowsum);

    finalize_kernel<<<32, 256, 0, stream>>>(rowsum, pospart, out);
}